// Round 11
// baseline (283.444 us; speedup 1.0000x reference)
//
#include <hip/hip_runtime.h>
#include <hip/hip_bf16.h>

// Problem constants
#define HIDDEN   4096
#define N_HEADS  32
#define N_KV     8
#define N_REP    4
#define HEAD_DIM 128
#define CACHE    4096
#define BATCH    32

#define PJ_THREADS 128
#define PJ_COLS    512     // per block: 64 col-threads x 8 cols
#define PJ_HCHUNK  128     // K-chunk per block (grid.y = 4096/128 = 32)

typedef float f4v __attribute__((ext_vector_type(4)));

// ---------------------------------------------------------------------------
// Skinny GEMM: part[hc][b][col] = sum_{h in chunk} X[b][h] * W[h][col], M=32.
// R11 structure: 8 cols/thread (2x f4v weight loads/row) + 4-row batches +
// 2-way batch split (wave0 = b0-15, wave1 = b16-31). Per-thread LDS reads
// unchanged (512) but threads halved vs R10 -> total LDS-pipe work halves
// again (12.8 -> 6.4 us/CU proj1). Grid (10|8, 32) = 320|256 blocks keeps
// >=1 block/CU (per-CU BW demand unchanged ~25 GB/s — R9 lesson).
// VGPR ~210 (acc 128, wc/wn 64) fits launch_bounds(128,2) without spill.
// ---------------------------------------------------------------------------
__global__ __launch_bounds__(128, 2) void proj_kernel(
    const float* __restrict__ X,           // [32][4096]
    const float* __restrict__ W1, int ld1, int ncol1,
    const float* __restrict__ W2, int ld2,
    float* __restrict__ part, int ncols)
{
    __shared__ float xs[32 * PJ_HCHUNK];   // 16 KB
    const int hc   = blockIdx.y;           // 0..31
    const int h0   = hc * PJ_HCHUNK;
    const int col0 = blockIdx.x * PJ_COLS;
    const int tid  = threadIdx.x;

    for (int i = tid * 4; i < 32 * PJ_HCHUNK; i += PJ_THREADS * 4) {
        int b = i >> 7, j = i & 127;
        *(float4*)&xs[i] = *(const float4*)&X[(size_t)b * HIDDEN + h0 + j];
    }
    __syncthreads();

    const int bg  = tid >> 6;              // 0..1 : batch half (wave-uniform)
    const int ct  = tid & 63;
    const int col = col0 + ct * 8;         // 8 cols; block spans 512 cols,
                                           // ncol1 % 512 == 0 so no straddle
    const float* xbase = xs + bg * 16 * PJ_HCHUNK;

    const float* Wp;
    size_t ld;
    if (col < ncol1) { Wp = W1 + (size_t)h0 * ld1 + col;           ld = ld1; }
    else             { Wp = W2 + (size_t)h0 * ld2 + (col - ncol1); ld = ld2; }

    f4v accL[16], accH[16];
#pragma unroll
    for (int b = 0; b < 16; ++b) { accL[b] = 0.f; accH[b] = 0.f; }

    f4v wcL[4], wcH[4], wnL[4], wnH[4];
#pragma unroll
    for (int r = 0; r < 4; ++r) {
        wcL[r] = *(const f4v*)(Wp + r * ld);
        wcH[r] = *(const f4v*)(Wp + r * ld + 4);
    }
    Wp += 4 * ld;

#define PJ_COMPUTE(XR)                                                  \
    _Pragma("unroll")                                                   \
    for (int b = 0; b < 16; ++b) {                                      \
        float4 xv = *(const float4*)((XR) + b * PJ_HCHUNK);             \
        accL[b] += wcL[0] * xv.x;  accH[b] += wcH[0] * xv.x;            \
        accL[b] += wcL[1] * xv.y;  accH[b] += wcH[1] * xv.y;            \
        accL[b] += wcL[2] * xv.z;  accH[b] += wcH[2] * xv.z;            \
        accL[b] += wcL[3] * xv.w;  accH[b] += wcH[3] * xv.w;            \
    }

    for (int bt = 0; bt < (PJ_HCHUNK / 4) - 1; ++bt) {
#pragma unroll
        for (int r = 0; r < 4; ++r) {
            wnL[r] = *(const f4v*)(Wp + r * ld);
            wnH[r] = *(const f4v*)(Wp + r * ld + 4);
        }
        const float* xr = xbase + bt * 4;
        PJ_COMPUTE(xr)
#pragma unroll
        for (int r = 0; r < 4; ++r) { wcL[r] = wnL[r]; wcH[r] = wnH[r]; }
        Wp += 4 * ld;
    }
    {
        const float* xr = xbase + PJ_HCHUNK - 4;
        PJ_COMPUTE(xr)
    }
#undef PJ_COMPUTE

    // part[hc][b][col]; b = bg*16 + i. 2 KB contiguous per store-pair/wave
    float* dst = part + ((size_t)hc * 32 + bg * 16) * ncols + col;
#pragma unroll
    for (int b = 0; b < 16; ++b) {
        *(f4v*)(dst + (size_t)b * ncols)     = accL[b];
        *(f4v*)(dst + (size_t)b * ncols + 4) = accH[b];
    }
}

// Sum 32 h-chunk partials. grid = (ncols/256, 32)
__global__ __launch_bounds__(256) void combine_proj(
    const float* __restrict__ part, int ncols,
    float* __restrict__ dst1, int ld1, int ncol1,
    float* __restrict__ dst2, int ld2)
{
    const int col = blockIdx.x * 256 + threadIdx.x;
    const int b   = blockIdx.y;
    float s = 0.f;
#pragma unroll
    for (int i = 0; i < 32; ++i) s += part[((size_t)i * 32 + b) * ncols + col];
    if (col < ncol1) dst1[(size_t)b * ld1 + col] = s;
    else             dst2[(size_t)b * ld2 + (col - ncol1)] = s;
}

// ---------------------------------------------------------------------------
// Decode attention — byte-identical to round 8/10 (at HBM roofline ~6.5 TB/s).
// ---------------------------------------------------------------------------

template<int CTRL>
__device__ __forceinline__ float dpp_ror(float x) {
    return __int_as_float(__builtin_amdgcn_update_dpp(
        0, __float_as_int(x), CTRL, 0xF, 0xF, true));
}

#define DOT4(S, Q, K)                              \
    S = Q.x * K.x;                                 \
    S = fmaf(Q.y, K.y, S);                         \
    S = fmaf(Q.z, K.z, S);                         \
    S = fmaf(Q.w, K.w, S);

// row_ror:n = 0x120 + n ; rotate-reduce within each 16-lane row
#define RED8_DPP(CTRL)                             \
    sA0 += dpp_ror<CTRL>(sA0);                     \
    sA1 += dpp_ror<CTRL>(sA1);                     \
    sA2 += dpp_ror<CTRL>(sA2);                     \
    sA3 += dpp_ror<CTRL>(sA3);                     \
    sB0 += dpp_ror<CTRL>(sB0);                     \
    sB1 += dpp_ror<CTRL>(sB1);                     \
    sB2 += dpp_ror<CTRL>(sB2);                     \
    sB3 += dpp_ror<CTRL>(sB3);

#define REDV(V, M)                                 \
    V.x += __shfl_xor(V.x, M, 64);                 \
    V.y += __shfl_xor(V.y, M, 64);                 \
    V.z += __shfl_xor(V.z, M, 64);                 \
    V.w += __shfl_xor(V.w, M, 64);

__global__ __launch_bounds__(256, 8) void attn_kernel(
    const float* __restrict__ q,      // [32][4096], col = (kv*4+r)*128+d
    const float* __restrict__ kc,     // [32][8][4096][128]
    const float* __restrict__ vc,
    float* __restrict__ po,
    float* __restrict__ pl)
{
    const int bid   = blockIdx.x;      // 0..2047
    const int pair  = bid >> 3;        // 0..255
    const int sg    = bid & 7;
    const int tid   = threadIdx.x;
    const int w     = tid >> 6;
    const int lane  = tid & 63;
    const int h     = lane >> 5;       // which key of the row-pair
    const int c     = lane & 31;       // 4-float chunk of head_dim
    const int split = sg * 4 + w;      // 0..31
    const int b     = pair >> 3;
    const int kv    = pair & 7;

    // q fragments: lane holds q[r][c*4..c*4+3], pre-scaled by rsqrt(128)*log2e
    const float SCL = 0.08838834764831845f * 1.4426950408889634f;
    const float* qbp = q + (size_t)b * HIDDEN + kv * 512 + c * 4;
    f4v q0 = *(const f4v*)(qbp);
    f4v q1 = *(const f4v*)(qbp + 128);
    f4v q2 = *(const f4v*)(qbp + 256);
    f4v q3 = *(const f4v*)(qbp + 384);
    q0 *= SCL; q1 *= SCL; q2 *= SCL; q3 *= SCL;

    const size_t base = (size_t)(b * N_KV + kv) * CACHE * HEAD_DIM;
    const int j0 = split * 128;        // first key of this split
    const float* kp = kc + base + (size_t)(j0 + h) * HEAD_DIM + c * 4;
    const float* vp = vc + base + (size_t)(j0 + h) * HEAD_DIM + c * 4;

    // accumulators: out[r][c*4..+3] for this half's keys; lac per row
    f4v o0 = 0.f, o1 = 0.f, o2 = 0.f, o3 = 0.f;
    f4v lacv = 0.f;

    for (int it = 0; it < 32; ++it) {
        // 4 fully-coalesced 1 KB loads (keys j+h, j+2+h for K and V)
        f4v ka = __builtin_nontemporal_load((const f4v*)kp);
        f4v kb = __builtin_nontemporal_load((const f4v*)(kp + 256));
        f4v va = __builtin_nontemporal_load((const f4v*)vp);
        f4v vb = __builtin_nontemporal_load((const f4v*)(vp + 256));

        float sA0, sA1, sA2, sA3, sB0, sB1, sB2, sB3;
        DOT4(sA0, q0, ka)  DOT4(sA1, q1, ka)
        DOT4(sA2, q2, ka)  DOT4(sA3, q3, ka)
        DOT4(sB0, q0, kb)  DOT4(sB1, q1, kb)
        DOT4(sB2, q2, kb)  DOT4(sB3, q3, kb)

        // reduce over the 32 lanes of this half (4 DPP stages + xor16)
        RED8_DPP(0x121)   // row_ror:1
        RED8_DPP(0x122)   // row_ror:2
        RED8_DPP(0x124)   // row_ror:4
        RED8_DPP(0x128)   // row_ror:8
        sA0 += __shfl_xor(sA0, 16, 64);
        sA1 += __shfl_xor(sA1, 16, 64);
        sA2 += __shfl_xor(sA2, 16, 64);
        sA3 += __shfl_xor(sA3, 16, 64);
        sB0 += __shfl_xor(sB0, 16, 64);
        sB1 += __shfl_xor(sB1, 16, 64);
        sB2 += __shfl_xor(sB2, 16, 64);
        sB3 += __shfl_xor(sB3, 16, 64);

        float pA0 = __builtin_amdgcn_exp2f(sA0);
        float pA1 = __builtin_amdgcn_exp2f(sA1);
        float pA2 = __builtin_amdgcn_exp2f(sA2);
        float pA3 = __builtin_amdgcn_exp2f(sA3);
        float pB0 = __builtin_amdgcn_exp2f(sB0);
        float pB1 = __builtin_amdgcn_exp2f(sB1);
        float pB2 = __builtin_amdgcn_exp2f(sB2);
        float pB3 = __builtin_amdgcn_exp2f(sB3);

        lacv.x += pA0 + pB0;
        lacv.y += pA1 + pB1;
        lacv.z += pA2 + pB2;
        lacv.w += pA3 + pB3;

        o0.x = fmaf(pA0, va.x, o0.x); o0.x = fmaf(pB0, vb.x, o0.x);
        o0.y = fmaf(pA0, va.y, o0.y); o0.y = fmaf(pB0, vb.y, o0.y);
        o0.z = fmaf(pA0, va.z, o0.z); o0.z = fmaf(pB0, vb.z, o0.z);
        o0.w = fmaf(pA0, va.w, o0.w); o0.w = fmaf(pB0, vb.w, o0.w);
        o1.x = fmaf(pA1, va.x, o1.x); o1.x = fmaf(pB1, vb.x, o1.x);
        o1.y = fmaf(pA1, va.y, o1.y); o1.y = fmaf(pB1, vb.y, o1.y);
        o1.z = fmaf(pA1, va.z, o1.z); o1.z = fmaf(pB1, vb.z, o1.z);
        o1.w = fmaf(pA1, va.w, o1.w); o1.w = fmaf(pB1, vb.w, o1.w);
        o2.x = fmaf(pA2, va.x, o2.x); o2.x = fmaf(pB2, vb.x, o2.x);
        o2.y = fmaf(pA2, va.y, o2.y); o2.y = fmaf(pB2, vb.y, o2.y);
        o2.z = fmaf(pA2, va.z, o2.z); o2.z = fmaf(pB2, vb.z, o2.z);
        o2.w = fmaf(pA2, va.w, o2.w); o2.w = fmaf(pB2, vb.w, o2.w);
        o3.x = fmaf(pA3, va.x, o3.x); o3.x = fmaf(pB3, vb.x, o3.x);
        o3.y = fmaf(pA3, va.y, o3.y); o3.y = fmaf(pB3, vb.y, o3.y);
        o3.z = fmaf(pA3, va.z, o3.z); o3.z = fmaf(pB3, vb.z, o3.z);
        o3.w = fmaf(pA3, va.w, o3.w); o3.w = fmaf(pB3, vb.w, o3.w);

        kp += 512; vp += 512;
    }

    // combine the two halves (epilogue only)
    REDV(o0, 32) REDV(o1, 32) REDV(o2, 32) REDV(o3, 32) REDV(lacv, 32)

    // half 0 writes rows 0,1; half 1 writes rows 2,3 (identical data in both)
    f4v w0 = h ? o2 : o0;              // row 2h
    f4v w1 = h ? o3 : o1;              // row 2h+1
    float* pod = po + (((size_t)pair * 32 + split) * 4 + 2 * h) * 128 + c * 4;
    *(f4v*)pod         = w0;
    *(f4v*)(pod + 128) = w1;
    if (lane == 0)
        *(f4v*)(pl + ((size_t)pair * 32 + split) * 4) = lacv;
}

// Sum 32 split partials, divide, add v_new. 512 blocks x 256 threads.
__global__ __launch_bounds__(256) void combine_attn(
    const float* __restrict__ po, const float* __restrict__ pl,
    const float* __restrict__ vnew, float* __restrict__ attnc)
{
    const int t    = blockIdx.x * 256 + threadIdx.x;  // 0..131071
    const int pair = t >> 9;
    const int rem  = t & 511;
    const int r    = rem >> 7;
    const int d    = rem & 127;
    const int b    = pair >> 3;
    const int kv   = pair & 7;

    float os = 0.f, ls = 0.f;
#pragma unroll 4
    for (int s = 0; s < 32; ++s) {
        os += po[(((size_t)pair * 32 + s) * 4 + r) * 128 + d];
        ls += pl[((size_t)pair * 32 + s) * 4 + r];
    }
    float val = os / ls + vnew[(size_t)b * (N_KV * HEAD_DIM) + kv * 128 + d];
    attnc[(size_t)b * HIDDEN + kv * 512 + r * 128 + d] = val;
}

// ---------------------------------------------------------------------------
extern "C" void kernel_launch(void* const* d_in, const int* in_sizes, int n_in,
                              void* d_out, int out_size, void* d_ws, size_t ws_size,
                              hipStream_t stream)
{
    const float* x   = (const float*)d_in[0];
    const float* kc  = (const float*)d_in[1];
    const float* vc  = (const float*)d_in[2];
    const float* wq  = (const float*)d_in[3];
    // d_in[4] = wk : dead in the reference (k_new never used) — skipped.
    const float* wv  = (const float*)d_in[5];
    const float* wo  = (const float*)d_in[6];
    float* out = (float*)d_out;

    // workspace layout (floats) — scratch region S reused serially:
    //   pA (proj1 partials, 5.24M) -> po+pl (attn partials, 4.23M) -> pC (4.19M)
    float* ws    = (float*)d_ws;
    float* q     = ws;                    // 131072
    float* vnew  = ws + 131072;           // 32768
    float* attnc = ws + 163840;           // 131072
    float* S     = ws + 294912;
    float* pA    = S;                     // 32*32*5120 = 5242880
    float* po    = S;                     // 256*32*4*128 = 4194304 (after pA dead)
    float* pl    = S + 4194304;           // 32768
    float* pC    = S;                     // 32*32*4096 = 4194304 (after po dead)

    // 1) q = x@wq, v_new = x@wv (fused, 5120 columns)
    proj_kernel<<<dim3(10, 32), PJ_THREADS, 0, stream>>>(x, wq, 4096, 4096, wv, 1024, pA, 5120);
    combine_proj<<<dim3(20, 32), 256, 0, stream>>>(pA, 5120, q, 4096, 4096, vnew, 1024);

    // 2) attention over KV cache
    attn_kernel<<<2048, 256, 0, stream>>>(q, kc, vc, po, pl);
    combine_attn<<<512, 256, 0, stream>>>(po, pl, vnew, attnc);

    // 3) out = attn @ wo
    proj_kernel<<<dim3(8, 32), PJ_THREADS, 0, stream>>>(attnc, wo, 4096, 4096, wo, 4096, pC, 4096);
    combine_proj<<<dim3(16, 32), 256, 0, stream>>>(pC, 4096, out, 4096, 4096, out, 4096);
}

// Round 12
// 242.125 us; speedup vs baseline: 1.1707x; 1.1707x over previous
//
#include <hip/hip_runtime.h>
#include <hip/hip_bf16.h>

// Problem constants
#define HIDDEN   4096
#define N_HEADS  32
#define N_KV     8
#define N_REP    4
#define HEAD_DIM 128
#define CACHE    4096
#define BATCH    32

#define PJ_THREADS 128
#define PJ_COLS    128     // per block: 32 col-threads x 4 cols
#define PJ_HCHUNK  128     // K-chunk per block (grid.y = 4096/128 = 32)

typedef float f4v __attribute__((ext_vector_type(4)));

// ---------------------------------------------------------------------------
// Skinny GEMM: part[hc][b][col] = sum_{h in chunk} X[b][h] * W[h][col], M=32.
// R12 structure: R10's proven inner loop (4 cols/thread, 8-row batches,
// depth-1 prefetch) with perfectly balanced grids and higher occupancy.
//   128 threads = 4 half-wave groups (bg2 = tid>>5): group g = batches
//   g*8..g*8+7, cols (tid&31)*4. Per ds_read_b128: 2 addresses/wave (2-way
//   bank aliasing = free, m136) -> total LDS instrs unchanged vs R10.
//   proj1 grid (40,32)=1280 blocks = 5.0/CU exact; proj2 (32,32)=4.0/CU.
//   ~115 VGPR -> 2.5 waves/SIMD resident (2x R10's latency cover).
// ---------------------------------------------------------------------------
__global__ __launch_bounds__(128, 3) void proj_kernel(
    const float* __restrict__ X,           // [32][4096]
    const float* __restrict__ W1, int ld1, int ncol1,
    const float* __restrict__ W2, int ld2,
    float* __restrict__ part, int ncols)
{
    __shared__ float xs[32 * PJ_HCHUNK];   // 16 KB
    const int hc   = blockIdx.y;           // 0..31
    const int h0   = hc * PJ_HCHUNK;
    const int col0 = blockIdx.x * PJ_COLS;
    const int tid  = threadIdx.x;

    for (int i = tid * 4; i < 32 * PJ_HCHUNK; i += PJ_THREADS * 4) {
        int b = i >> 7, j = i & 127;
        *(float4*)&xs[i] = *(const float4*)&X[(size_t)b * HIDDEN + h0 + j];
    }
    __syncthreads();

    const int bg2 = tid >> 5;              // 0..3 : batch group (half-wave)
    const int ct  = tid & 31;
    const int col = col0 + ct * 4;
    const float* xbase = xs + bg2 * 8 * PJ_HCHUNK;

    const float* Wp;
    size_t ld;
    if (col < ncol1) { Wp = W1 + (size_t)h0 * ld1 + col;           ld = ld1; }
    else             { Wp = W2 + (size_t)h0 * ld2 + (col - ncol1); ld = ld2; }

    f4v acc[8];
#pragma unroll
    for (int b = 0; b < 8; ++b) acc[b] = 0.f;

    f4v wc[8], wn[8];
#pragma unroll
    for (int r = 0; r < 8; ++r) wc[r] = *(const f4v*)(Wp + r * ld);
    Wp += 8 * ld;

#define PJ_COMPUTE(XR)                                                  \
    _Pragma("unroll")                                                   \
    for (int b = 0; b < 8; ++b) {                                       \
        float4 x0 = *(const float4*)((XR) + b * PJ_HCHUNK);             \
        float4 x1 = *(const float4*)((XR) + b * PJ_HCHUNK + 4);         \
        acc[b] += wc[0] * x0.x;                                         \
        acc[b] += wc[1] * x0.y;                                         \
        acc[b] += wc[2] * x0.z;                                         \
        acc[b] += wc[3] * x0.w;                                         \
        acc[b] += wc[4] * x1.x;                                         \
        acc[b] += wc[5] * x1.y;                                         \
        acc[b] += wc[6] * x1.z;                                         \
        acc[b] += wc[7] * x1.w;                                         \
    }

    for (int bt = 0; bt < (PJ_HCHUNK / 8) - 1; ++bt) {
#pragma unroll
        for (int r = 0; r < 8; ++r) wn[r] = *(const f4v*)(Wp + r * ld);
        const float* xr = xbase + bt * 8;
        PJ_COMPUTE(xr)
#pragma unroll
        for (int r = 0; r < 8; ++r) wc[r] = wn[r];
        Wp += 8 * ld;
    }
    {
        const float* xr = xbase + PJ_HCHUNK - 8;
        PJ_COMPUTE(xr)
    }
#undef PJ_COMPUTE

    // part[hc][b][col]; b = bg2*8 + i. 512 B contiguous per half-wave store
    float* dst = part + ((size_t)hc * 32 + bg2 * 8) * ncols + col;
#pragma unroll
    for (int b = 0; b < 8; ++b)
        *(f4v*)(dst + (size_t)b * ncols) = acc[b];
}

// Sum 32 h-chunk partials. grid = (ncols/256, 32)
__global__ __launch_bounds__(256) void combine_proj(
    const float* __restrict__ part, int ncols,
    float* __restrict__ dst1, int ld1, int ncol1,
    float* __restrict__ dst2, int ld2)
{
    const int col = blockIdx.x * 256 + threadIdx.x;
    const int b   = blockIdx.y;
    float s = 0.f;
#pragma unroll
    for (int i = 0; i < 32; ++i) s += part[((size_t)i * 32 + b) * ncols + col];
    if (col < ncol1) dst1[(size_t)b * ld1 + col] = s;
    else             dst2[(size_t)b * ld2 + (col - ncol1)] = s;
}

// ---------------------------------------------------------------------------
// Decode attention — byte-identical to round 8/10 (at HBM roofline ~6.5 TB/s).
// ---------------------------------------------------------------------------

template<int CTRL>
__device__ __forceinline__ float dpp_ror(float x) {
    return __int_as_float(__builtin_amdgcn_update_dpp(
        0, __float_as_int(x), CTRL, 0xF, 0xF, true));
}

#define DOT4(S, Q, K)                              \
    S = Q.x * K.x;                                 \
    S = fmaf(Q.y, K.y, S);                         \
    S = fmaf(Q.z, K.z, S);                         \
    S = fmaf(Q.w, K.w, S);

// row_ror:n = 0x120 + n ; rotate-reduce within each 16-lane row
#define RED8_DPP(CTRL)                             \
    sA0 += dpp_ror<CTRL>(sA0);                     \
    sA1 += dpp_ror<CTRL>(sA1);                     \
    sA2 += dpp_ror<CTRL>(sA2);                     \
    sA3 += dpp_ror<CTRL>(sA3);                     \
    sB0 += dpp_ror<CTRL>(sB0);                     \
    sB1 += dpp_ror<CTRL>(sB1);                     \
    sB2 += dpp_ror<CTRL>(sB2);                     \
    sB3 += dpp_ror<CTRL>(sB3);

#define REDV(V, M)                                 \
    V.x += __shfl_xor(V.x, M, 64);                 \
    V.y += __shfl_xor(V.y, M, 64);                 \
    V.z += __shfl_xor(V.z, M, 64);                 \
    V.w += __shfl_xor(V.w, M, 64);

__global__ __launch_bounds__(256, 8) void attn_kernel(
    const float* __restrict__ q,      // [32][4096], col = (kv*4+r)*128+d
    const float* __restrict__ kc,     // [32][8][4096][128]
    const float* __restrict__ vc,
    float* __restrict__ po,
    float* __restrict__ pl)
{
    const int bid   = blockIdx.x;      // 0..2047
    const int pair  = bid >> 3;        // 0..255
    const int sg    = bid & 7;
    const int tid   = threadIdx.x;
    const int w     = tid >> 6;
    const int lane  = tid & 63;
    const int h     = lane >> 5;       // which key of the row-pair
    const int c     = lane & 31;       // 4-float chunk of head_dim
    const int split = sg * 4 + w;      // 0..31
    const int b     = pair >> 3;
    const int kv    = pair & 7;

    // q fragments: lane holds q[r][c*4..c*4+3], pre-scaled by rsqrt(128)*log2e
    const float SCL = 0.08838834764831845f * 1.4426950408889634f;
    const float* qbp = q + (size_t)b * HIDDEN + kv * 512 + c * 4;
    f4v q0 = *(const f4v*)(qbp);
    f4v q1 = *(const f4v*)(qbp + 128);
    f4v q2 = *(const f4v*)(qbp + 256);
    f4v q3 = *(const f4v*)(qbp + 384);
    q0 *= SCL; q1 *= SCL; q2 *= SCL; q3 *= SCL;

    const size_t base = (size_t)(b * N_KV + kv) * CACHE * HEAD_DIM;
    const int j0 = split * 128;        // first key of this split
    const float* kp = kc + base + (size_t)(j0 + h) * HEAD_DIM + c * 4;
    const float* vp = vc + base + (size_t)(j0 + h) * HEAD_DIM + c * 4;

    // accumulators: out[r][c*4..+3] for this half's keys; lac per row
    f4v o0 = 0.f, o1 = 0.f, o2 = 0.f, o3 = 0.f;
    f4v lacv = 0.f;

    for (int it = 0; it < 32; ++it) {
        // 4 fully-coalesced 1 KB loads (keys j+h, j+2+h for K and V)
        f4v ka = __builtin_nontemporal_load((const f4v*)kp);
        f4v kb = __builtin_nontemporal_load((const f4v*)(kp + 256));
        f4v va = __builtin_nontemporal_load((const f4v*)vp);
        f4v vb = __builtin_nontemporal_load((const f4v*)(vp + 256));

        float sA0, sA1, sA2, sA3, sB0, sB1, sB2, sB3;
        DOT4(sA0, q0, ka)  DOT4(sA1, q1, ka)
        DOT4(sA2, q2, ka)  DOT4(sA3, q3, ka)
        DOT4(sB0, q0, kb)  DOT4(sB1, q1, kb)
        DOT4(sB2, q2, kb)  DOT4(sB3, q3, kb)

        // reduce over the 32 lanes of this half (4 DPP stages + xor16)
        RED8_DPP(0x121)   // row_ror:1
        RED8_DPP(0x122)   // row_ror:2
        RED8_DPP(0x124)   // row_ror:4
        RED8_DPP(0x128)   // row_ror:8
        sA0 += __shfl_xor(sA0, 16, 64);
        sA1 += __shfl_xor(sA1, 16, 64);
        sA2 += __shfl_xor(sA2, 16, 64);
        sA3 += __shfl_xor(sA3, 16, 64);
        sB0 += __shfl_xor(sB0, 16, 64);
        sB1 += __shfl_xor(sB1, 16, 64);
        sB2 += __shfl_xor(sB2, 16, 64);
        sB3 += __shfl_xor(sB3, 16, 64);

        float pA0 = __builtin_amdgcn_exp2f(sA0);
        float pA1 = __builtin_amdgcn_exp2f(sA1);
        float pA2 = __builtin_amdgcn_exp2f(sA2);
        float pA3 = __builtin_amdgcn_exp2f(sA3);
        float pB0 = __builtin_amdgcn_exp2f(sB0);
        float pB1 = __builtin_amdgcn_exp2f(sB1);
        float pB2 = __builtin_amdgcn_exp2f(sB2);
        float pB3 = __builtin_amdgcn_exp2f(sB3);

        lacv.x += pA0 + pB0;
        lacv.y += pA1 + pB1;
        lacv.z += pA2 + pB2;
        lacv.w += pA3 + pB3;

        o0.x = fmaf(pA0, va.x, o0.x); o0.x = fmaf(pB0, vb.x, o0.x);
        o0.y = fmaf(pA0, va.y, o0.y); o0.y = fmaf(pB0, vb.y, o0.y);
        o0.z = fmaf(pA0, va.z, o0.z); o0.z = fmaf(pB0, vb.z, o0.z);
        o0.w = fmaf(pA0, va.w, o0.w); o0.w = fmaf(pB0, vb.w, o0.w);
        o1.x = fmaf(pA1, va.x, o1.x); o1.x = fmaf(pB1, vb.x, o1.x);
        o1.y = fmaf(pA1, va.y, o1.y); o1.y = fmaf(pB1, vb.y, o1.y);
        o1.z = fmaf(pA1, va.z, o1.z); o1.z = fmaf(pB1, vb.z, o1.z);
        o1.w = fmaf(pA1, va.w, o1.w); o1.w = fmaf(pB1, vb.w, o1.w);
        o2.x = fmaf(pA2, va.x, o2.x); o2.x = fmaf(pB2, vb.x, o2.x);
        o2.y = fmaf(pA2, va.y, o2.y); o2.y = fmaf(pB2, vb.y, o2.y);
        o2.z = fmaf(pA2, va.z, o2.z); o2.z = fmaf(pB2, vb.z, o2.z);
        o2.w = fmaf(pA2, va.w, o2.w); o2.w = fmaf(pB2, vb.w, o2.w);
        o3.x = fmaf(pA3, va.x, o3.x); o3.x = fmaf(pB3, vb.x, o3.x);
        o3.y = fmaf(pA3, va.y, o3.y); o3.y = fmaf(pB3, vb.y, o3.y);
        o3.z = fmaf(pA3, va.z, o3.z); o3.z = fmaf(pB3, vb.z, o3.z);
        o3.w = fmaf(pA3, va.w, o3.w); o3.w = fmaf(pB3, vb.w, o3.w);

        kp += 512; vp += 512;
    }

    // combine the two halves (epilogue only)
    REDV(o0, 32) REDV(o1, 32) REDV(o2, 32) REDV(o3, 32) REDV(lacv, 32)

    // half 0 writes rows 0,1; half 1 writes rows 2,3 (identical data in both)
    f4v w0 = h ? o2 : o0;              // row 2h
    f4v w1 = h ? o3 : o1;              // row 2h+1
    float* pod = po + (((size_t)pair * 32 + split) * 4 + 2 * h) * 128 + c * 4;
    *(f4v*)pod         = w0;
    *(f4v*)(pod + 128) = w1;
    if (lane == 0)
        *(f4v*)(pl + ((size_t)pair * 32 + split) * 4) = lacv;
}

// Sum 32 split partials, divide, add v_new. 512 blocks x 256 threads.
__global__ __launch_bounds__(256) void combine_attn(
    const float* __restrict__ po, const float* __restrict__ pl,
    const float* __restrict__ vnew, float* __restrict__ attnc)
{
    const int t    = blockIdx.x * 256 + threadIdx.x;  // 0..131071
    const int pair = t >> 9;
    const int rem  = t & 511;
    const int r    = rem >> 7;
    const int d    = rem & 127;
    const int b    = pair >> 3;
    const int kv   = pair & 7;

    float os = 0.f, ls = 0.f;
#pragma unroll 4
    for (int s = 0; s < 32; ++s) {
        os += po[(((size_t)pair * 32 + s) * 4 + r) * 128 + d];
        ls += pl[((size_t)pair * 32 + s) * 4 + r];
    }
    float val = os / ls + vnew[(size_t)b * (N_KV * HEAD_DIM) + kv * 128 + d];
    attnc[(size_t)b * HIDDEN + kv * 512 + r * 128 + d] = val;
}

// ---------------------------------------------------------------------------
extern "C" void kernel_launch(void* const* d_in, const int* in_sizes, int n_in,
                              void* d_out, int out_size, void* d_ws, size_t ws_size,
                              hipStream_t stream)
{
    const float* x   = (const float*)d_in[0];
    const float* kc  = (const float*)d_in[1];
    const float* vc  = (const float*)d_in[2];
    const float* wq  = (const float*)d_in[3];
    // d_in[4] = wk : dead in the reference (k_new never used) — skipped.
    const float* wv  = (const float*)d_in[5];
    const float* wo  = (const float*)d_in[6];
    float* out = (float*)d_out;

    // workspace layout (floats) — scratch region S reused serially:
    //   pA (proj1 partials, 5.24M) -> po+pl (attn partials, 4.23M) -> pC (4.19M)
    float* ws    = (float*)d_ws;
    float* q     = ws;                    // 131072
    float* vnew  = ws + 131072;           // 32768
    float* attnc = ws + 163840;           // 131072
    float* S     = ws + 294912;
    float* pA    = S;                     // 32*32*5120 = 5242880
    float* po    = S;                     // 256*32*4*128 = 4194304 (after pA dead)
    float* pl    = S + 4194304;           // 32768
    float* pC    = S;                     // 32*32*4096 = 4194304 (after po dead)

    // 1) q = x@wq, v_new = x@wv (fused, 5120 columns)
    proj_kernel<<<dim3(40, 32), PJ_THREADS, 0, stream>>>(x, wq, 4096, 4096, wv, 1024, pA, 5120);
    combine_proj<<<dim3(20, 32), 256, 0, stream>>>(pA, 5120, q, 4096, 4096, vnew, 1024);

    // 2) attention over KV cache
    attn_kernel<<<2048, 256, 0, stream>>>(q, kc, vc, po, pl);
    combine_attn<<<512, 256, 0, stream>>>(po, pl, vnew, attnc);

    // 3) out = attn @ wo
    proj_kernel<<<dim3(32, 32), PJ_THREADS, 0, stream>>>(attnc, wo, 4096, 4096, wo, 4096, pC, 4096);
    combine_proj<<<dim3(16, 32), 256, 0, stream>>>(pC, 4096, out, 4096, 4096, out, 4096);
}